// Round 11
// baseline (4137.865 us; speedup 1.0000x reference)
//
#include <hip/hip_runtime.h>

// LSTM B=64 T=512 I=512 H=1024 — round 10: sentinel pipeline + parity red.
// Round-9b tripwire diagnosis: REAL RACE. A wave's h-poll set usually excludes
// its OWN block's chunk, so a non-gate wave can finish step t+1's poll and
// overwrite red[mt][w] while its own gate wave still reads step-t values
// (timing-dependent corruption -> nondeterministic output). Fix: restore the
// parity dimension red[t&1][...] (80 KB LDS, 1 block/CU). Parity suffices:
// a wave reaches its step-t+2 red write only after __syncthreads(t+1), which
// the gate passes only after completing its step-t red reads.
// Everything else unchanged from round 9b:
//  - NO counters/barriers. h ring slots pre-poisoned 0xFFFF (unreachable:
//    |h|<1 => data u16 < 0xC000). Consumers poll the DATA: re-issue their 16
//    coherent b128 loads until no u16 is 0xFFFF (s |= w&(w<<1) bit trick).
//  - 8-slot ring; gate re-poisons slot (t+5)&7 (dead h_{t-3}) each step; acks
//    ride the next step's h-load vmcnt(0).

typedef short bf16x8 __attribute__((ext_vector_type(8)));
typedef float f32x4  __attribute__((ext_vector_type(4)));
typedef unsigned u32x4 __attribute__((ext_vector_type(4)));

#define BB 64
#define TT 512
#define II 512
#define HH 1024

#define NBLK 256
#define NTHR 512

#define HSLOT 65536                          // u16 per ring slot (128*64*8)
#define XT_STRIDE 32768                      // u16 per timestep of x

// ws layout (bytes)
#define WS_HRH_OFF 0                         // hH ring [8][H/8][B][8] u16 = 1 MB
#define WS_HRL_OFF (1 << 20)                 // hL ring, 1 MB
#define WS_XPH_OFF (4 << 20)                 // xH [T][I/8][B][8] u16 = 32 MB
#define WS_XPL_OFF ((4 << 20) + (32 << 20))  // xL, 32 MB

__device__ __forceinline__ float fast_sigmoid(float x) {
    return 1.0f / (1.0f + __expf(-x));
}
__device__ __forceinline__ float fast_tanh(float x) {
    x = fminf(15.0f, fmaxf(-15.0f, x));
    const float e = __expf(2.0f * x);
    return (e - 1.0f) / (e + 1.0f);
}

// fp32 -> bf16 hi + bf16 lo-of-residual (RNE both)
__device__ __forceinline__ void split_bf16(float x, unsigned& hi, unsigned& lo)
{
    unsigned b = __float_as_uint(x);
    hi = (b + 0x7fffu + ((b >> 16) & 1u)) >> 16;
    float r = x - __uint_as_float(hi << 16);
    unsigned bl = __float_as_uint(r);
    lo = (bl + 0x7fffu + ((bl >> 16) & 1u)) >> 16;
}

#define MFMA(A, B, C) __builtin_amdgcn_mfma_f32_16x16x32_bf16((A), (B), (C), 0, 0, 0)

// coherent 16B load (bypass L1+L2), issued WITHOUT wait
__device__ __forceinline__ void issue_coh(const unsigned short* p, u32x4& d)
{
    asm volatile("global_load_dwordx4 %0, %1, off sc0 sc1" : "=v"(d) : "v"(p));
}
// u16 store, agent-scope write-through (ring is only ever read with sc0 sc1)
__device__ __forceinline__ void store_u16(unsigned short* p, unsigned short v)
{
    __hip_atomic_store(p, v, __ATOMIC_RELAXED, __HIP_MEMORY_SCOPE_AGENT);
}

// x -> split planes, layout [t][k>>3][b][k&7] u16 per plane
__global__ void __launch_bounds__(256)
transpose_pack_x(const float* __restrict__ x,
                 unsigned short* __restrict__ xH, unsigned short* __restrict__ xL)
{
    __shared__ float tile[64][65];
    const int t   = (int)blockIdx.x;
    const int tid = (int)threadIdx.x;
    const int li  = tid & 63;
    const int w4  = tid >> 6;

    for (int kc = 0; kc < II; kc += 64) {
#pragma unroll
        for (int r = 0; r < 16; ++r) {
            const int b = w4 * 16 + r;
            tile[b][li] = x[((size_t)b * TT + t) * II + kc + li];
        }
        __syncthreads();
#pragma unroll
        for (int half = 0; half < 2; ++half) {
            const int u  = tid + half * 256;      // u = k8*64 + b
            const int k8 = u >> 6, b = u & 63;
            unsigned short oh[8], ol[8];
#pragma unroll
            for (int e = 0; e < 8; ++e) {
                unsigned hi, lo;
                split_bf16(tile[b][k8 * 8 + e], hi, lo);
                oh[e] = (unsigned short)hi;
                ol[e] = (unsigned short)lo;
            }
            const size_t idx = (size_t)t * XT_STRIDE + ((kc >> 3) + k8) * 512 + b * 8;
            *(uint4*)(xH + idx) = *(const uint4*)oh;
            *(uint4*)(xL + idx) = *(const uint4*)ol;
        }
        __syncthreads();
    }
}

__global__ void __launch_bounds__(NTHR, 2)   // <=256 VGPR, 1 block/CU
lstm_mfma(const unsigned short* __restrict__ xH,
          const unsigned short* __restrict__ xL,
          const int*   __restrict__ lens,
          const float* __restrict__ Wih,     // [4H][I]
          const float* __restrict__ Whh,     // [4H][H]
          const float* __restrict__ bih,
          const float* __restrict__ bhh,
          unsigned short* __restrict__ hH,   // ring [8][H/8][B][8]
          unsigned short* __restrict__ hL,
          float* __restrict__ out)           // [B][H]
{
    __shared__ float red[2][2][8][2][16][20];  // [pa][mt][src][nt][bsub][pad20] = 80 KB

    const int tid  = (int)threadIdx.x;
    const int l    = tid & 63;
    const int w    = __builtin_amdgcn_readfirstlane(tid >> 6);  // wave = K-slice
    const int bsub = l & 15;
    const int q    = l >> 4;                 // quad

    const int jt = (int)blockIdx.x >> 1;     // owns j [8jt, 8jt+8)
    const int bh = (int)blockIdx.x & 1;
    const int j0 = jt * 8;

    const int bofs[2] = {(bh * 32 + bsub) * 8, (bh * 32 + 16 + bsub) * 8};

    // ---- weight A-fragments -> registers, both m-tiles (persist across t) ----
    bf16x8 wxh[2][2], wxl[2][2];   // [xi][mt]
    bf16x8 whh[4][2], whl[4][2];   // [hi2][mt]
#pragma unroll
    for (int mt = 0; mt < 2; ++mt) {
        const int row = (l & 3) * HH + j0 + mt * 4 + ((l & 15) >> 2);
#pragma unroll
        for (int xi = 0; xi < 2; ++xi) {
            const float* src = Wih + (size_t)row * II + (2 * w + xi) * 32 + q * 8;
            const float4 w0 = *(const float4*)src;
            const float4 w1 = *(const float4*)(src + 4);
            const float wf[8] = {w0.x, w0.y, w0.z, w0.w, w1.x, w1.y, w1.z, w1.w};
#pragma unroll
            for (int e = 0; e < 8; ++e) {
                unsigned hi, lo;
                split_bf16(wf[e], hi, lo);
                wxh[xi][mt][e] = (short)hi;
                wxl[xi][mt][e] = (short)lo;
            }
        }
#pragma unroll
        for (int hi2 = 0; hi2 < 4; ++hi2) {
            const float* src = Whh + (size_t)row * HH + (4 * w + hi2) * 32 + q * 8;
            const float4 w0 = *(const float4*)src;
            const float4 w1 = *(const float4*)(src + 4);
            const float wf[8] = {w0.x, w0.y, w0.z, w0.w, w1.x, w1.y, w1.z, w1.w};
#pragma unroll
            for (int e = 0; e < 8; ++e) {
                unsigned hi, lo;
                split_bf16(wf[e], hi, lo);
                whh[hi2][mt][e] = (short)hi;
                whl[hi2][mt][e] = (short)lo;
            }
        }
    }

    // ---- gate-wave state: wave 0 owns mt0, wave 4 owns mt1 ----
    const int gw = (w == 0) ? 0 : (w == 4) ? 1 : -1;
    float bias[4], c[2] = {0.f, 0.f}, lasth[2] = {0.f, 0.f};
    int len[2] = {0, 0};
    const int jlow  = (gw >= 0) ? gw * 4 + q : 0;
    const int jcell = j0 + jlow;

    if (gw >= 0) {
#pragma unroll
        for (int g = 0; g < 4; ++g)
            bias[g] = bih[g * HH + jcell] + bhh[g * HH + jcell];
#pragma unroll
        for (int nt = 0; nt < 2; ++nt) {
            const int b = bh * 32 + nt * 16 + bsub;
            len[nt] = lens[b];
            store_u16(hH + (size_t)jt * 512 + b * 8 + jlow, 0);  // h_0 = 0, slot 0
            store_u16(hL + (size_t)jt * 512 + b * 8 + jlow, 0);
        }
        // no ack needed: consumers poll the data itself
    }

    for (int t = 0; t < TT; ++t) {
        // ---- x-part: plain cached b128 loads (independent of h_t) ----
        f32x4 s0[2][2], s1[2][2];            // [mt][nt]
#pragma unroll
        for (int mt = 0; mt < 2; ++mt)
#pragma unroll
            for (int nt = 0; nt < 2; ++nt)
                s0[mt][nt] = s1[mt][nt] = (f32x4){0.f, 0.f, 0.f, 0.f};
        {
            const unsigned short* xh = xH + (size_t)t * XT_STRIDE;
            const unsigned short* xl = xL + (size_t)t * XT_STRIDE;
#pragma unroll
            for (int xi = 0; xi < 2; ++xi) {
                const int idx = ((2 * w + xi) * 4 + q) * 512;
#pragma unroll
                for (int nt = 0; nt < 2; ++nt) {
                    const bf16x8 ahi = *(const bf16x8*)(xh + idx + bofs[nt]);
                    const bf16x8 alo = *(const bf16x8*)(xl + idx + bofs[nt]);
#pragma unroll
                    for (int mt = 0; mt < 2; ++mt) {
                        s0[mt][nt] = MFMA(wxh[xi][mt], ahi, s0[mt][nt]);
                        s1[mt][nt] = MFMA(wxh[xi][mt], alo, s1[mt][nt]);
                        s1[mt][nt] = MFMA(wxl[xi][mt], ahi, s1[mt][nt]);
                    }
                }
            }
        }

        // ---- h-part: sentinel-poll my 16 coherent b128 frags, then MFMA ----
        const unsigned short* hph = hH + (size_t)(t & 7) * HSLOT;
        const unsigned short* hpl = hL + (size_t)(t & 7) * HSLOT;
        u32x4 fh[4][2], fl[4][2];
        while (true) {
#pragma unroll
            for (int hi2 = 0; hi2 < 4; ++hi2) {
                const int idx = ((4 * w + hi2) * 4 + q) * 512;
#pragma unroll
                for (int nt = 0; nt < 2; ++nt) {
                    issue_coh(hph + idx + bofs[nt], fh[hi2][nt]);
                    issue_coh(hpl + idx + bofs[nt], fl[hi2][nt]);
                }
            }
            asm volatile("s_waitcnt vmcnt(0)"
                : "+v"(fh[0][0]), "+v"(fh[0][1]), "+v"(fh[1][0]), "+v"(fh[1][1]),
                  "+v"(fh[2][0]), "+v"(fh[2][1]), "+v"(fh[3][0]), "+v"(fh[3][1]),
                  "+v"(fl[0][0]), "+v"(fl[0][1]), "+v"(fl[1][0]), "+v"(fl[1][1]),
                  "+v"(fl[2][0]), "+v"(fl[2][1]), "+v"(fl[3][0]), "+v"(fl[3][1])
                :: "memory");
            // sentinel test: any u16 == 0xFFFF?  Data u16 < 0xC000 (|h|<1), so
            // bits 15&14 both set only for the 0xFFFF sentinel:
            //   s |= w & (w<<1);  sentinel present iff s & 0x80008000.
            unsigned s = 0u;
#pragma unroll
            for (int hi2 = 0; hi2 < 4; ++hi2)
#pragma unroll
                for (int nt = 0; nt < 2; ++nt)
#pragma unroll
                    for (int i = 0; i < 4; ++i) {
                        const unsigned a = fh[hi2][nt][i], b2 = fl[hi2][nt][i];
                        s |= a & (a << 1);
                        s |= b2 & (b2 << 1);
                    }
            if (__all((s & 0x80008000u) == 0u)) break;
            __builtin_amdgcn_s_sleep(1);
        }
#pragma unroll
        for (int hi2 = 0; hi2 < 4; ++hi2) {
#pragma unroll
            for (int nt = 0; nt < 2; ++nt) {
                const bf16x8 ahi = __builtin_bit_cast(bf16x8, fh[hi2][nt]);
                const bf16x8 alo = __builtin_bit_cast(bf16x8, fl[hi2][nt]);
#pragma unroll
                for (int mt = 0; mt < 2; ++mt) {
                    s0[mt][nt] = MFMA(whh[hi2][mt], ahi, s0[mt][nt]);
                    s1[mt][nt] = MFMA(whh[hi2][mt], alo, s1[mt][nt]);
                    s1[mt][nt] = MFMA(whl[hi2][mt], ahi, s1[mt][nt]);
                }
            }
        }

        // ---- vectorized 8-source reduction (b128, 16B-aligned, PARITY) ----
        const int pa = t & 1;
#pragma unroll
        for (int mt = 0; mt < 2; ++mt)
#pragma unroll
            for (int nt = 0; nt < 2; ++nt)
                *(f32x4*)&red[pa][mt][w][nt][bsub][4 * q] = s0[mt][nt] + s1[mt][nt];
        __syncthreads();

        // ---- gate tail (waves 0,4): b128 red reads, gate, store, re-poison ----
        if (gw >= 0) {
            const int slot  = (t + 1) & 7;
            const int pslot = (t + 5) & 7;   // holds dead h_{t-3}: re-poison
            unsigned short* dsth = hH + (size_t)slot * HSLOT + jt * 512;
            unsigned short* dstl = hL + (size_t)slot * HSLOT + jt * 512;
            unsigned short* sth  = hH + (size_t)pslot * HSLOT + jt * 512;
            unsigned short* stl  = hL + (size_t)pslot * HSLOT + jt * 512;
#pragma unroll
            for (int nt = 0; nt < 2; ++nt) {
                f32x4 g4 = (f32x4){bias[0], bias[1], bias[2], bias[3]};
#pragma unroll
                for (int src = 0; src < 8; ++src)
                    g4 += *(f32x4*)&red[pa][gw][src][nt][bsub][4 * q];
                const float ig = fast_sigmoid(g4[0]);
                const float fg = fast_sigmoid(g4[1]);
                const float gg = fast_tanh(g4[2]);
                const float og = fast_sigmoid(g4[3]);
                c[nt] = fg * c[nt] + ig * gg;
                const float h = og * fast_tanh(c[nt]);
                unsigned hi, lo;
                split_bf16(h, hi, lo);
                const int b = bh * 32 + nt * 16 + bsub;
                store_u16(sth + b * 8 + jlow, 0xFFFFu);   // poison future slot
                store_u16(stl + b * 8 + jlow, 0xFFFFu);
                store_u16(dsth + b * 8 + jlow, (unsigned short)hi);   // publish
                store_u16(dstl + b * 8 + jlow, (unsigned short)lo);
                if (t == len[nt] - 1) lasth[nt] = h;
            }
            // no vmcnt: poison-ack rides next step's h-load vmcnt(0), long
            // before slot reuse at t+4; data needs no ack (polled directly).
        }
    }

    // ---- epilogue ----
    if (gw >= 0) {
#pragma unroll
        for (int nt = 0; nt < 2; ++nt) {
            const int b = bh * 32 + nt * 16 + bsub;
            out[(size_t)b * HH + jcell] = lasth[nt];
        }
    }
}

extern "C" void kernel_launch(void* const* d_in, const int* in_sizes, int n_in,
                              void* d_out, int out_size, void* d_ws, size_t ws_size,
                              hipStream_t stream)
{
    const float* seq  = (const float*)d_in[0];
    const int*   lens = (const int*)  d_in[1];
    const float* Wih  = (const float*)d_in[2];
    const float* Whh  = (const float*)d_in[3];
    const float* bih  = (const float*)d_in[4];
    const float* bhh  = (const float*)d_in[5];
    float* out = (float*)d_out;

    char* ws = (char*)d_ws;
    unsigned short* hH = (unsigned short*)(ws + WS_HRH_OFF);
    unsigned short* hL = (unsigned short*)(ws + WS_HRL_OFF);
    unsigned short* xH = (unsigned short*)(ws + WS_XPH_OFF);
    unsigned short* xL = (unsigned short*)(ws + WS_XPL_OFF);

    // poison the whole h ring (slot 0 then gets real h_0 zeros from the kernel)
    (void)hipMemsetAsync(ws, 0xFF, (size_t)2 * HSLOT * 8 * sizeof(unsigned short),
                         stream);
    transpose_pack_x<<<dim3(TT), dim3(256), 0, stream>>>(seq, xH, xL);
    lstm_mfma<<<dim3(NBLK), dim3(NTHR), 0, stream>>>(xH, xL, lens, Wih, Whh, bih, bhh,
                                                     hH, hL, out);
}

// Round 12
// 4109.115 us; speedup vs baseline: 1.0070x; 1.0070x over previous
//
#include <hip/hip_runtime.h>

// LSTM B=64 T=512 I=512 H=1024 — round 12: flag-array sync (no RMW, no
// sentinel re-loads) + r8 dedup K-slices + r11 parity reduction.
// Measured history: r7 3.27ms (counter RMW chains, racy red), r8 3.47 (racy),
// r11 4.14 (safe, but sentinel polling re-fetched all data per retry:
// FETCH/WRITE ballooned). This round:
//  - publish: gate wave stores t+2 into its OWN flag dword (plain coherent
//    store after vmcnt(0) ack of h stores) — zero RMW serialization.
//  - poll: wave w consumes h rows [128w,128w+128) produced by blocks
//    jt in [16w,16w+16) x 2 gate waves = 32 flags; ONE coherent dword load
//    per lane (2 lines) + __all(v >= t+1). Data loaded exactly once after.
//  - h ring: 4 slots. Safety: block P reaches gate(t) only after all its 8
//    waves passed poll(t); union of their flag sets = ALL 256 domain flags
//    >= t+1 => every block finished reading h_{t-1} => overwriting slot
//    (t+1)&3 is safe (2 slots would suffice; 4 for margin).
//  - red: parity-indexed [t&1], pad-20 b128 (the r9b race fix, kept).
//  - domains: bh = blockIdx&1 gives two fully independent 128-block
//    recurrences (b-halves), already XCD-interleaved.

typedef short bf16x8 __attribute__((ext_vector_type(8)));
typedef float f32x4  __attribute__((ext_vector_type(4)));
typedef unsigned u32x4 __attribute__((ext_vector_type(4)));

#define BB 64
#define TT 512
#define II 512
#define HH 1024

#define NBLK 256
#define NTHR 512

#define HSLOT 65536                          // u16 per ring slot (128*64*8)
#define XT_STRIDE 32768                      // u16 per timestep of x

// ws layout (bytes)
#define WS_FLag_OFF 0                        // flags int[2][1024] (8 KB, memset 0)
#define WS_HRH_OFF (1 << 20)                 // hH ring [4][H/8][B][8] u16 = 512 KB
#define WS_HRL_OFF ((1 << 20) + (512 << 10)) // hL ring, 512 KB
#define WS_XPH_OFF (4 << 20)                 // xH [T][I/8][B][8] u16 = 32 MB
#define WS_XPL_OFF ((4 << 20) + (32 << 20))  // xL, 32 MB

__device__ __forceinline__ float fast_sigmoid(float x) {
    return 1.0f / (1.0f + __expf(-x));
}
__device__ __forceinline__ float fast_tanh(float x) {
    x = fminf(15.0f, fmaxf(-15.0f, x));
    const float e = __expf(2.0f * x);
    return (e - 1.0f) / (e + 1.0f);
}

// fp32 -> bf16 hi + bf16 lo-of-residual (RNE both)
__device__ __forceinline__ void split_bf16(float x, unsigned& hi, unsigned& lo)
{
    unsigned b = __float_as_uint(x);
    hi = (b + 0x7fffu + ((b >> 16) & 1u)) >> 16;
    float r = x - __uint_as_float(hi << 16);
    unsigned bl = __float_as_uint(r);
    lo = (bl + 0x7fffu + ((bl >> 16) & 1u)) >> 16;
}

#define MFMA(A, B, C) __builtin_amdgcn_mfma_f32_16x16x32_bf16((A), (B), (C), 0, 0, 0)

// coherent 16B load (bypass stale L1/L2), issued WITHOUT wait
__device__ __forceinline__ void issue_coh(const unsigned short* p, u32x4& d)
{
    asm volatile("global_load_dwordx4 %0, %1, off sc0 sc1" : "=v"(d) : "v"(p));
}
__device__ __forceinline__ void store_u16(unsigned short* p, unsigned short v)
{
    __hip_atomic_store(p, v, __ATOMIC_RELAXED, __HIP_MEMORY_SCOPE_AGENT);
}
__device__ __forceinline__ void store_flag(int* p, int v)
{
    __hip_atomic_store(p, v, __ATOMIC_RELAXED, __HIP_MEMORY_SCOPE_AGENT);
}
__device__ __forceinline__ int load_flag(const int* p)
{
    return __hip_atomic_load(p, __ATOMIC_RELAXED, __HIP_MEMORY_SCOPE_AGENT);
}

// x -> split planes, layout [t][k>>3][b][k&7] u16 per plane
__global__ void __launch_bounds__(256)
transpose_pack_x(const float* __restrict__ x,
                 unsigned short* __restrict__ xH, unsigned short* __restrict__ xL)
{
    __shared__ float tile[64][65];
    const int t   = (int)blockIdx.x;
    const int tid = (int)threadIdx.x;
    const int li  = tid & 63;
    const int w4  = tid >> 6;

    for (int kc = 0; kc < II; kc += 64) {
#pragma unroll
        for (int r = 0; r < 16; ++r) {
            const int b = w4 * 16 + r;
            tile[b][li] = x[((size_t)b * TT + t) * II + kc + li];
        }
        __syncthreads();
#pragma unroll
        for (int half = 0; half < 2; ++half) {
            const int u  = tid + half * 256;      // u = k8*64 + b
            const int k8 = u >> 6, b = u & 63;
            unsigned short oh[8], ol[8];
#pragma unroll
            for (int e = 0; e < 8; ++e) {
                unsigned hi, lo;
                split_bf16(tile[b][k8 * 8 + e], hi, lo);
                oh[e] = (unsigned short)hi;
                ol[e] = (unsigned short)lo;
            }
            const size_t idx = (size_t)t * XT_STRIDE + ((kc >> 3) + k8) * 512 + b * 8;
            *(uint4*)(xH + idx) = *(const uint4*)oh;
            *(uint4*)(xL + idx) = *(const uint4*)ol;
        }
        __syncthreads();
    }
}

__global__ void __launch_bounds__(NTHR, 2)   // <=256 VGPR, 1 block/CU
lstm_mfma(const unsigned short* __restrict__ xH,
          const unsigned short* __restrict__ xL,
          const int*   __restrict__ lens,
          const float* __restrict__ Wih,     // [4H][I]
          const float* __restrict__ Whh,     // [4H][H]
          const float* __restrict__ bih,
          const float* __restrict__ bhh,
          unsigned short* __restrict__ hH,   // ring [4][H/8][B][8]
          unsigned short* __restrict__ hL,
          int*   __restrict__ flags,         // [2][1024] ints (256 used/domain)
          float* __restrict__ out)           // [B][H]
{
    __shared__ float red[2][2][8][2][16][20];  // [pa][mt][src][nt][bsub][pad20] = 80 KB

    const int tid  = (int)threadIdx.x;
    const int l    = tid & 63;
    const int w    = __builtin_amdgcn_readfirstlane(tid >> 6);  // wave = K-slice
    const int bsub = l & 15;
    const int q    = l >> 4;                 // quad

    const int jt = (int)blockIdx.x >> 1;     // owns j [8jt, 8jt+8)
    const int bh = (int)blockIdx.x & 1;
    const int j0 = jt * 8;

    const int bofs[2] = {(bh * 32 + bsub) * 8, (bh * 32 + 16 + bsub) * 8};

    int* fbase = flags + bh * 1024;

    // ---- weight A-fragments -> registers, both m-tiles (persist across t) ----
    bf16x8 wxh[2][2], wxl[2][2];   // [xi][mt]
    bf16x8 whh[4][2], whl[4][2];   // [hi2][mt]
#pragma unroll
    for (int mt = 0; mt < 2; ++mt) {
        const int row = (l & 3) * HH + j0 + mt * 4 + ((l & 15) >> 2);
#pragma unroll
        for (int xi = 0; xi < 2; ++xi) {
            const float* src = Wih + (size_t)row * II + (2 * w + xi) * 32 + q * 8;
            const float4 w0 = *(const float4*)src;
            const float4 w1 = *(const float4*)(src + 4);
            const float wf[8] = {w0.x, w0.y, w0.z, w0.w, w1.x, w1.y, w1.z, w1.w};
#pragma unroll
            for (int e = 0; e < 8; ++e) {
                unsigned hi, lo;
                split_bf16(wf[e], hi, lo);
                wxh[xi][mt][e] = (short)hi;
                wxl[xi][mt][e] = (short)lo;
            }
        }
#pragma unroll
        for (int hi2 = 0; hi2 < 4; ++hi2) {
            const float* src = Whh + (size_t)row * HH + (4 * w + hi2) * 32 + q * 8;
            const float4 w0 = *(const float4*)src;
            const float4 w1 = *(const float4*)(src + 4);
            const float wf[8] = {w0.x, w0.y, w0.z, w0.w, w1.x, w1.y, w1.z, w1.w};
#pragma unroll
            for (int e = 0; e < 8; ++e) {
                unsigned hi, lo;
                split_bf16(wf[e], hi, lo);
                whh[hi2][mt][e] = (short)hi;
                whl[hi2][mt][e] = (short)lo;
            }
        }
    }

    // ---- gate-wave state: wave 0 owns mt0, wave 4 owns mt1 ----
    const int gw = (w == 0) ? 0 : (w == 4) ? 1 : -1;
    float bias[4], c[2] = {0.f, 0.f}, lasth[2] = {0.f, 0.f};
    int len[2] = {0, 0};
    const int jlow  = (gw >= 0) ? gw * 4 + q : 0;
    const int jcell = j0 + jlow;
    int* myflag = fbase + jt * 2 + gw;       // this gate wave's own dword

    if (gw >= 0) {
#pragma unroll
        for (int g = 0; g < 4; ++g)
            bias[g] = bih[g * HH + jcell] + bhh[g * HH + jcell];
#pragma unroll
        for (int nt = 0; nt < 2; ++nt) {
            const int b = bh * 32 + nt * 16 + bsub;
            len[nt] = lens[b];
            store_u16(hH + (size_t)jt * 512 + b * 8 + jlow, 0);  // h_0 = 0, slot 0
            store_u16(hL + (size_t)jt * 512 + b * 8 + jlow, 0);
        }
        asm volatile("s_waitcnt vmcnt(0)" ::: "memory");  // h_0 globally visible
        if (l == 0) store_flag(myflag, 1);                // publish h_0
    }

    // wave w consumes rows produced by blocks jt' in [16w,16w+16): flags
    // [32w, 32w+32). Two lanes per flag (l&31).
    const int* pollp = fbase + 32 * w + (l & 31);

    for (int t = 0; t < TT; ++t) {
        // ---- x-part: plain cached b128 loads (independent of h_t) ----
        f32x4 s0[2][2], s1[2][2];            // [mt][nt]
#pragma unroll
        for (int mt = 0; mt < 2; ++mt)
#pragma unroll
            for (int nt = 0; nt < 2; ++nt)
                s0[mt][nt] = s1[mt][nt] = (f32x4){0.f, 0.f, 0.f, 0.f};
        {
            const unsigned short* xh = xH + (size_t)t * XT_STRIDE;
            const unsigned short* xl = xL + (size_t)t * XT_STRIDE;
#pragma unroll
            for (int xi = 0; xi < 2; ++xi) {
                const int idx = ((2 * w + xi) * 4 + q) * 512;
#pragma unroll
                for (int nt = 0; nt < 2; ++nt) {
                    const bf16x8 ahi = *(const bf16x8*)(xh + idx + bofs[nt]);
                    const bf16x8 alo = *(const bf16x8*)(xl + idx + bofs[nt]);
#pragma unroll
                    for (int mt = 0; mt < 2; ++mt) {
                        s0[mt][nt] = MFMA(wxh[xi][mt], ahi, s0[mt][nt]);
                        s1[mt][nt] = MFMA(wxh[xi][mt], alo, s1[mt][nt]);
                        s1[mt][nt] = MFMA(wxl[xi][mt], ahi, s1[mt][nt]);
                    }
                }
            }
        }

        // ---- poll my 32 producers' flags (one coherent dword/lane, 2 lines) ----
        {
            const int need = t + 1;
            while (true) {
                const int v = load_flag(pollp);
                if (__all(v >= need)) break;
                __builtin_amdgcn_s_sleep(1);
            }
            asm volatile("" ::: "memory");
        }

        // ---- h-part: 32 coherent b128 loads, ONE batch, ONE wait ----
        const unsigned short* hph = hH + (size_t)(t & 3) * HSLOT;
        const unsigned short* hpl = hL + (size_t)(t & 3) * HSLOT;
        u32x4 fh[4][2], fl[4][2];
#pragma unroll
        for (int hi2 = 0; hi2 < 4; ++hi2) {
            const int idx = ((4 * w + hi2) * 4 + q) * 512;
#pragma unroll
            for (int nt = 0; nt < 2; ++nt) {
                issue_coh(hph + idx + bofs[nt], fh[hi2][nt]);
                issue_coh(hpl + idx + bofs[nt], fl[hi2][nt]);
            }
        }
        asm volatile("s_waitcnt vmcnt(0)"
            : "+v"(fh[0][0]), "+v"(fh[0][1]), "+v"(fh[1][0]), "+v"(fh[1][1]),
              "+v"(fh[2][0]), "+v"(fh[2][1]), "+v"(fh[3][0]), "+v"(fh[3][1]),
              "+v"(fl[0][0]), "+v"(fl[0][1]), "+v"(fl[1][0]), "+v"(fl[1][1]),
              "+v"(fl[2][0]), "+v"(fl[2][1]), "+v"(fl[3][0]), "+v"(fl[3][1])
            :: "memory");
#pragma unroll
        for (int hi2 = 0; hi2 < 4; ++hi2) {
#pragma unroll
            for (int nt = 0; nt < 2; ++nt) {
                const bf16x8 ahi = __builtin_bit_cast(bf16x8, fh[hi2][nt]);
                const bf16x8 alo = __builtin_bit_cast(bf16x8, fl[hi2][nt]);
#pragma unroll
                for (int mt = 0; mt < 2; ++mt) {
                    s0[mt][nt] = MFMA(whh[hi2][mt], ahi, s0[mt][nt]);
                    s1[mt][nt] = MFMA(whh[hi2][mt], alo, s1[mt][nt]);
                    s1[mt][nt] = MFMA(whl[hi2][mt], ahi, s1[mt][nt]);
                }
            }
        }

        // ---- vectorized 8-source reduction (b128, 16B-aligned, PARITY) ----
        const int pa = t & 1;
#pragma unroll
        for (int mt = 0; mt < 2; ++mt)
#pragma unroll
            for (int nt = 0; nt < 2; ++nt)
                *(f32x4*)&red[pa][mt][w][nt][bsub][4 * q] = s0[mt][nt] + s1[mt][nt];
        __syncthreads();

        // ---- gate tail (waves 0,4): red reads, gate, h store, flag publish ----
        if (gw >= 0) {
            const int slot = (t + 1) & 3;
            unsigned short* dsth = hH + (size_t)slot * HSLOT + jt * 512;
            unsigned short* dstl = hL + (size_t)slot * HSLOT + jt * 512;
#pragma unroll
            for (int nt = 0; nt < 2; ++nt) {
                f32x4 g4 = (f32x4){bias[0], bias[1], bias[2], bias[3]};
#pragma unroll
                for (int src = 0; src < 8; ++src)
                    g4 += *(f32x4*)&red[pa][gw][src][nt][bsub][4 * q];
                const float ig = fast_sigmoid(g4[0]);
                const float fg = fast_sigmoid(g4[1]);
                const float gg = fast_tanh(g4[2]);
                const float og = fast_sigmoid(g4[3]);
                c[nt] = fg * c[nt] + ig * gg;
                const float h = og * fast_tanh(c[nt]);
                unsigned hi, lo;
                split_bf16(h, hi, lo);
                const int b = bh * 32 + nt * 16 + bsub;
                store_u16(dsth + b * 8 + jlow, (unsigned short)hi);
                store_u16(dstl + b * 8 + jlow, (unsigned short)lo);
                if (t == len[nt] - 1) lasth[nt] = h;
            }
            asm volatile("s_waitcnt vmcnt(0)" ::: "memory");  // h_{t+1} visible
            if (l == 0) store_flag(myflag, t + 2);            // publish (no RMW)
        }
    }

    // ---- epilogue ----
    if (gw >= 0) {
#pragma unroll
        for (int nt = 0; nt < 2; ++nt) {
            const int b = bh * 32 + nt * 16 + bsub;
            out[(size_t)b * HH + jcell] = lasth[nt];
        }
    }
}

extern "C" void kernel_launch(void* const* d_in, const int* in_sizes, int n_in,
                              void* d_out, int out_size, void* d_ws, size_t ws_size,
                              hipStream_t stream)
{
    const float* seq  = (const float*)d_in[0];
    const int*   lens = (const int*)  d_in[1];
    const float* Wih  = (const float*)d_in[2];
    const float* Whh  = (const float*)d_in[3];
    const float* bih  = (const float*)d_in[4];
    const float* bhh  = (const float*)d_in[5];
    float* out = (float*)d_out;

    char* ws = (char*)d_ws;
    int*            flags = (int*)           (ws + WS_FLag_OFF);
    unsigned short* hH    = (unsigned short*)(ws + WS_HRH_OFF);
    unsigned short* hL    = (unsigned short*)(ws + WS_HRL_OFF);
    unsigned short* xH    = (unsigned short*)(ws + WS_XPH_OFF);
    unsigned short* xL    = (unsigned short*)(ws + WS_XPL_OFF);

    (void)hipMemsetAsync(flags, 0, 8192, stream);   // monotonic flags start at 0
    transpose_pack_x<<<dim3(TT), dim3(256), 0, stream>>>(seq, xH, xL);
    lstm_mfma<<<dim3(NBLK), dim3(NTHR), 0, stream>>>(xH, xL, lens, Wih, Whh, bih, bhh,
                                                     hH, hL, flags, out);
}